// Round 1
// baseline (377.340 us; speedup 1.0000x reference)
//
#include <hip/hip_runtime.h>
#include <math.h>

#define N_NODES 100000
#define N_EDGES 3200000
#define F_IN    256
#define D_OUT   128

typedef __attribute__((ext_vector_type(8))) short short8;
typedef __attribute__((ext_vector_type(4))) float f32x4;

__device__ __forceinline__ unsigned short f2bf(float f) {
    unsigned u = __float_as_uint(f);
    unsigned r = (u + 0x7FFFu + ((u >> 16) & 1u)) >> 16;   // RNE
    return (unsigned short)r;
}

__device__ __forceinline__ float dot4(f32x4 a, f32x4 b) {
    return a.x * b.x + a.y * b.y + a.z * b.z + a.w * b.w;
}

// signed byte k (0..3) of u, as float
__device__ __forceinline__ float sb(unsigned u, int k) {
    return (float)((int)(u << ((3 - k) * 8)) >> 24);
}

// ---------------------------------------------------------------------------
// Kernel A: 256 blocks x 128 threads. Block kk:
//   - kbT[n][kk] = bf16(kern[kk][n])  (coalesced read of kern row kk)
//   - wave 0 computes v1[kk] = W1[kk]@w2, v2[kk] = W1[kk]@w3
// ---------------------------------------------------------------------------
__global__ __launch_bounds__(128) void prep_kernel(
    const float* __restrict__ W1, const float* __restrict__ w2,
    const float* __restrict__ w3, const float* __restrict__ kern,
    float* __restrict__ v1, float* __restrict__ v2,
    unsigned short* __restrict__ kbT) {
    const int kk  = blockIdx.x;    // 0..255
    const int tid = threadIdx.x;   // 0..127
    kbT[(size_t)tid * F_IN + kk] = f2bf(kern[(size_t)kk * D_OUT + tid]);
    if (tid < 64) {
        const float* wr = W1 + (size_t)kk * D_OUT;
        float a = wr[tid], b = wr[tid + 64];
        float s1 = a * w2[tid] + b * w2[tid + 64];
        float s2 = a * w3[tid] + b * w3[tid + 64];
#pragma unroll
        for (int o = 32; o > 0; o >>= 1) {
            s1 += __shfl_xor(s1, o);
            s2 += __shfl_xor(s2, o);
        }
        if (tid == 0) { v1[kk] = s1; v2[kk] = s2; }
    }
}

// ---------------------------------------------------------------------------
// Kernel B: CSR row pointers via binary search over sorted edge_row.
// ---------------------------------------------------------------------------
__global__ void row_ptr_kernel(const int* __restrict__ edge_row,
                               int* __restrict__ row_ptr) {
    int r = blockIdx.x * blockDim.x + threadIdx.x;
    if (r > N_NODES) return;
    int lo = 0, hi = N_EDGES;
    while (lo < hi) {
        int mid = (lo + hi) >> 1;
        if (edge_row[mid] < r) lo = mid + 1; else hi = mid;
    }
    row_ptr[r] = lo;
}

// ---------------------------------------------------------------------------
// Kernel C: bf16 MFMA GEMM; epilogue quantizes value rows to int8 with
// per-row absmax scale (valq + scale). Fused fp32 sa1/sa2.
// x is streamed exactly once -> nontemporal loads keep L2/L3 clean for the
// attn kernel's gather tables.
// ---------------------------------------------------------------------------
__global__ __launch_bounds__(256) void gemm_sa_kernel(
    const float* __restrict__ x, const unsigned short* __restrict__ kbT,
    const float* __restrict__ v1, const float* __restrict__ v2,
    const float* __restrict__ b2p, const float* __restrict__ b3p,
    signed char* __restrict__ valq, float* __restrict__ scale,
    float* __restrict__ sa1, float* __restrict__ sa2) {
    const int wid = blockIdx.x * 4 + (threadIdx.x >> 6);
    const int m_base = wid * 32;
    if (m_base >= N_NODES) return;
    const int lane = threadIdx.x & 63;
    const int r = lane & 15;
    const int q = lane >> 4;

    const f32x4* x0 = (const f32x4*)(x + (size_t)(m_base + r) * F_IN + q * 8);
    const f32x4* x1 = (const f32x4*)(x + (size_t)(m_base + 16 + r) * F_IN + q * 8);

    f32x4 acc[2][8];
#pragma unroll
    for (int t = 0; t < 2; ++t)
#pragma unroll
        for (int nt = 0; nt < 8; ++nt) acc[t][nt] = (f32x4)(0.f);
    float s1a = 0.f, s1b = 0.f, s2a = 0.f, s2b = 0.f;

#pragma unroll 2
    for (int s = 0; s < 8; ++s) {            // K-steps of 32
        f32x4 p00 = __builtin_nontemporal_load(x0 + s * 8);
        f32x4 p01 = __builtin_nontemporal_load(x0 + s * 8 + 1);
        f32x4 p10 = __builtin_nontemporal_load(x1 + s * 8);
        f32x4 p11 = __builtin_nontemporal_load(x1 + s * 8 + 1);
        const f32x4* vp1 = (const f32x4*)(v1 + s * 32 + q * 8);
        const f32x4* vp2 = (const f32x4*)(v2 + s * 32 + q * 8);
        f32x4 va = vp1[0], vb = vp1[1], vc = vp2[0], vd = vp2[1];
        s1a += dot4(p00, va) + dot4(p01, vb);
        s2a += dot4(p00, vc) + dot4(p01, vd);
        s1b += dot4(p10, va) + dot4(p11, vb);
        s2b += dot4(p10, vc) + dot4(p11, vd);

        short8 a0, a1;
        a0[0] = (short)f2bf(p00.x); a0[1] = (short)f2bf(p00.y);
        a0[2] = (short)f2bf(p00.z); a0[3] = (short)f2bf(p00.w);
        a0[4] = (short)f2bf(p01.x); a0[5] = (short)f2bf(p01.y);
        a0[6] = (short)f2bf(p01.z); a0[7] = (short)f2bf(p01.w);
        a1[0] = (short)f2bf(p10.x); a1[1] = (short)f2bf(p10.y);
        a1[2] = (short)f2bf(p10.z); a1[3] = (short)f2bf(p10.w);
        a1[4] = (short)f2bf(p11.x); a1[5] = (short)f2bf(p11.y);
        a1[6] = (short)f2bf(p11.z); a1[7] = (short)f2bf(p11.w);

#pragma unroll
        for (int nt = 0; nt < 8; ++nt) {
            const short8 b = *(const short8*)(kbT + (size_t)(nt * 16 + r) * F_IN
                                              + s * 32 + q * 8);
            acc[0][nt] = __builtin_amdgcn_mfma_f32_16x16x32_bf16(a0, b, acc[0][nt], 0, 0, 0);
            acc[1][nt] = __builtin_amdgcn_mfma_f32_16x16x32_bf16(a1, b, acc[1][nt], 0, 0, 0);
        }
    }

    s1a += __shfl_xor(s1a, 16); s1a += __shfl_xor(s1a, 32);
    s1b += __shfl_xor(s1b, 16); s1b += __shfl_xor(s1b, 32);
    s2a += __shfl_xor(s2a, 16); s2a += __shfl_xor(s2a, 32);
    s2b += __shfl_xor(s2b, 16); s2b += __shfl_xor(s2b, 32);
    if (q == 0) {
        float bb2 = b2p[0], bb3 = b3p[0];
        sa1[m_base + r]      = s1a + bb2;
        sa1[m_base + 16 + r] = s1b + bb2;
        sa2[m_base + r]      = s2a + bb3;
        sa2[m_base + 16 + r] = s2b + bb3;
    }

    // epilogue: per-row absmax -> int8 quantize + scale store
#pragma unroll
    for (int t = 0; t < 2; ++t)
#pragma unroll
        for (int reg = 0; reg < 4; ++reg) {
            float m = 0.f;
#pragma unroll
            for (int nt = 0; nt < 8; ++nt) m = fmaxf(m, fabsf(acc[t][nt][reg]));
            m = fmaxf(m, __shfl_xor(m, 1));
            m = fmaxf(m, __shfl_xor(m, 2));
            m = fmaxf(m, __shfl_xor(m, 4));
            m = fmaxf(m, __shfl_xor(m, 8));
            const int row = m_base + t * 16 + q * 4 + reg;
            const float inv = m > 0.f ? 127.f / m : 0.f;
            if (r == 0) scale[row] = m * (1.f / 127.f);
#pragma unroll
            for (int nt = 0; nt < 8; ++nt) {
                int iq = (int)rintf(acc[t][nt][reg] * inv);
                valq[(size_t)row * D_OUT + nt * 16 + r] = (signed char)iq;
            }
        }
}

// ---------------------------------------------------------------------------
// Kernel D: fused softmax + SpMM, two-phase per row.
// One wave per row.
//   Phase 1 (per chunk of <=64 edges): lane l owns edge s+base+l. Coalesced
//     nontemporal loads of edge_col/adj; ONE gather of sa2[c]/scale[c] per
//     edge (vs 16 redundant before); computes ex and scale-folded weight
//     w = ex*scale[c]. Per-lane partial softmax denominator.
//   Phase 2: 4 edges/iter; (c,w) broadcast from owning lane via __shfl
//     (2 bpermutes / 4 edges). Only the valq gather remains in the dependent
//     chain -> unroll-4 keeps 4 gathers in flight.
// Streaming arrays (edge_col/adj/bias/out) are nontemporal so L2/L3 keep the
// hot gather tables (valq 12.8MB, sa2+scale 0.8MB).
// ---------------------------------------------------------------------------
__global__ __launch_bounds__(256) void attn_agg_kernel(
    const int* __restrict__ row_ptr, const int* __restrict__ edge_col,
    const float* __restrict__ adj, const float* __restrict__ sa1,
    const float* __restrict__ sa2, const signed char* __restrict__ valq,
    const float* __restrict__ scale, const float* __restrict__ bias,
    float* __restrict__ out) {
    const int lane = threadIdx.x & 63;
    int row = blockIdx.x * 4 + (threadIdx.x >> 6);
    if (row >= N_NODES) return;
    row = __builtin_amdgcn_readfirstlane(row);

    const int s   = row_ptr[row];
    const int cnt = row_ptr[row + 1] - s;
    const float sa1r = sa1[row];

    const int g = lane >> 4;
    const int r = lane & 15;
    const signed char* vbase = valq + r * 8;

    float acc[8];
#pragma unroll
    for (int j = 0; j < 8; ++j) acc[j] = 0.f;
    float sum = 0.f;

    for (int base = 0; base < cnt; base += 64) {
        const int n = min(64, cnt - base);

        // ---- phase 1: one lane per edge, coalesced ----
        int c = 0;
        float w = 0.f;
        if (lane < n) {
            const int e = s + base + lane;
            c = __builtin_nontemporal_load(edge_col + e);
            const float a = __builtin_nontemporal_load(adj + e);
            float t = a * (sa1r + sa2[c]);
            t = fmaxf(t, 0.2f * t);          // leaky_relu(0.2)
            const float ex = __expf(t);
            sum += ex;
            w = ex * scale[c];               // fold per-row dequant scale
        }

        // ---- phase 2: feature aggregation, 4 edges/iter ----
#pragma unroll 4
        for (int i = 0; i < n; i += 4) {
            const int   cc = __shfl(c, i + g);
            const float ww = __shfl(w, i + g);
            const uint2 p = *(const uint2*)(vbase + (size_t)cc * D_OUT);
            acc[0] += ww * sb(p.x, 0); acc[1] += ww * sb(p.x, 1);
            acc[2] += ww * sb(p.x, 2); acc[3] += ww * sb(p.x, 3);
            acc[4] += ww * sb(p.y, 0); acc[5] += ww * sb(p.y, 1);
            acc[6] += ww * sb(p.y, 2); acc[7] += ww * sb(p.y, 3);
        }
    }

    // denominator: full 64-lane reduce (lanes held disjoint edges)
    sum += __shfl_xor(sum, 1);
    sum += __shfl_xor(sum, 2);
    sum += __shfl_xor(sum, 4);
    sum += __shfl_xor(sum, 8);
    // acc: cross-group reduce (groups held disjoint edge subsets); share
    // the 16/32 stages with sum.
#pragma unroll
    for (int o = 16; o < 64; o <<= 1) {
        sum += __shfl_xor(sum, o);
#pragma unroll
        for (int j = 0; j < 8; ++j) acc[j] += __shfl_xor(acc[j], o);
    }
    const float inv = sum > 0.f ? 1.f / sum : 1.f;

    if (g == 0) {
        const f32x4* bp = (const f32x4*)(bias + (size_t)row * D_OUT + r * 8);
        f32x4 b0 = __builtin_nontemporal_load(bp);
        f32x4 b1 = __builtin_nontemporal_load(bp + 1);
        f32x4 r0, r1;
        r0.x = acc[0] * inv + b0.x; r0.y = acc[1] * inv + b0.y;
        r0.z = acc[2] * inv + b0.z; r0.w = acc[3] * inv + b0.w;
        r1.x = acc[4] * inv + b1.x; r1.y = acc[5] * inv + b1.y;
        r1.z = acc[6] * inv + b1.z; r1.w = acc[7] * inv + b1.w;
        f32x4* op = (f32x4*)(out + (size_t)row * D_OUT + r * 8);
        __builtin_nontemporal_store(r0, op);
        __builtin_nontemporal_store(r1, op + 1);
    }
}

// ---------------------------------------------------------------------------
extern "C" void kernel_launch(void* const* d_in, const int* in_sizes, int n_in,
                              void* d_out, int out_size, void* d_ws,
                              size_t ws_size, hipStream_t stream) {
    const float* x        = (const float*)d_in[0];
    const float* adj      = (const float*)d_in[1];
    const float* W1       = (const float*)d_in[2];
    const float* w2       = (const float*)d_in[3];
    const float* b2       = (const float*)d_in[4];
    const float* w3       = (const float*)d_in[5];
    const float* b3       = (const float*)d_in[6];
    const float* kern     = (const float*)d_in[7];
    const float* bias     = (const float*)d_in[8];
    const int*   edge_row = (const int*)d_in[9];
    const int*   edge_col = (const int*)d_in[10];
    float* out = (float*)d_out;

    signed char* valq = (signed char*)d_ws;                  // N*128 int8
    float* scale = (float*)(valq + (size_t)N_NODES * D_OUT); // N fp32
    float* sa1 = scale + N_NODES;                            // N fp32
    float* sa2 = sa1 + N_NODES;                              // N fp32
    int*   row_ptr = (int*)(sa2 + N_NODES);                  // N+1 (pad)
    float* v1 = (float*)(row_ptr + N_NODES + 4);             // 256
    float* v2 = v1 + F_IN;                                   // 256
    unsigned short* kbT = (unsigned short*)(v2 + F_IN);      // 128*256 bf16

    hipLaunchKernelGGL(prep_kernel, dim3(256), dim3(128), 0, stream,
                       W1, w2, w3, kern, v1, v2, kbT);
    hipLaunchKernelGGL(row_ptr_kernel, dim3((N_NODES + 1 + 255) / 256),
                       dim3(256), 0, stream, edge_row, row_ptr);
    hipLaunchKernelGGL(gemm_sa_kernel, dim3((N_NODES / 32 + 3) / 4), dim3(256),
                       0, stream, x, kbT, v1, v2, b2, b3, valq, scale, sa1,
                       sa2);
    hipLaunchKernelGGL(attn_agg_kernel, dim3(N_NODES / 4), dim3(256), 0,
                       stream, row_ptr, edge_col, adj, sa1, sa2, valq, scale,
                       bias, out);
}